// Round 10
// baseline (116.637 us; speedup 1.0000x reference)
//
#include <hip/hip_runtime.h>
#include <hip/hip_fp16.h>

// NCC loss: 9^3 box sums of {I, J, I*I, J*J, I*J}, per-voxel cc, -mean(cc).
// Dims: C=2, D=192, H=224, W=192, fp32. Full-volume two-pass:
//   K1 (k_hwsum): wave = one d-row strip. 48 active lanes x 4 px = W=192.
//     H-sum: running float4 sums + 9-deep NAMED-register I/J ring.
//     W-sum: wave-private LDS row, b128 taps (round-9 core).
//     NEW vs round 9 (targets vmcnt FIFO chaining of loads behind stores):
//       * 2-deep global prefetch (2 steps of slack before a load is consumed,
//         so prior stores can retire without stalling the consumer wait)
//       * stores staged in LDS for 2 rows, flushed every other step as
//         5 dwordx4 stores (768 B/inst, 4x fewer store instructions)
//       * HT1 28->14: 6144 waves = 6 waves/SIMD demand (was 3)
//   K2 (k_dsum): D-sum — barrier-free streaming register ring + cc + reduce.

#define C2   2
#define DDIM 192
#define HDIM 224
#define WDIM 192
#define HWN  (HDIM*WDIM)              // 43008
#define VOL  ((size_t)DDIM*HWN)       // 8257536
#define RAD  4
#define WINV (1.0f/729.0f)

#define HT1  14   // h-strip per wave (224/14 = 16 strips), even (pairs flush)

__device__ __forceinline__ float4 zero4() { float4 z; z.x=z.y=z.z=z.w=0.f; return z; }

__device__ __forceinline__ void padd(float4& r0, float4& r1, float4& r2,
                                     float4& r3, float4& r4,
                                     const float4 a, const float4 b) {
    r0.x+=a.x; r0.y+=a.y; r0.z+=a.z; r0.w+=a.w;
    r1.x+=b.x; r1.y+=b.y; r1.z+=b.z; r1.w+=b.w;
    r2.x=fmaf(a.x,a.x,r2.x); r2.y=fmaf(a.y,a.y,r2.y);
    r2.z=fmaf(a.z,a.z,r2.z); r2.w=fmaf(a.w,a.w,r2.w);
    r3.x=fmaf(b.x,b.x,r3.x); r3.y=fmaf(b.y,b.y,r3.y);
    r3.z=fmaf(b.z,b.z,r3.z); r3.w=fmaf(b.w,b.w,r3.w);
    r4.x=fmaf(a.x,b.x,r4.x); r4.y=fmaf(a.y,b.y,r4.y);
    r4.z=fmaf(a.z,b.z,r4.z); r4.w=fmaf(a.w,b.w,r4.w);
}
__device__ __forceinline__ void psub(float4& r0, float4& r1, float4& r2,
                                     float4& r3, float4& r4,
                                     const float4 a, const float4 b) {
    r0.x-=a.x; r0.y-=a.y; r0.z-=a.z; r0.w-=a.w;
    r1.x-=b.x; r1.y-=b.y; r1.z-=b.z; r1.w-=b.w;
    r2.x=fmaf(-a.x,a.x,r2.x); r2.y=fmaf(-a.y,a.y,r2.y);
    r2.z=fmaf(-a.z,a.z,r2.z); r2.w=fmaf(-a.w,a.w,r2.w);
    r3.x=fmaf(-b.x,b.x,r3.x); r3.y=fmaf(-b.y,b.y,r3.y);
    r3.z=fmaf(-b.z,b.z,r3.z); r3.w=fmaf(-b.w,b.w,r3.w);
    r4.x=fmaf(-a.x,b.x,r4.x); r4.y=fmaf(-a.y,b.y,r4.y);
    r4.z=fmaf(-a.z,b.z,r4.z); r4.w=fmaf(-a.w,b.w,r4.w);
}

// ---------------- K1: H-sum + W-sum of 5 product fields ----------------
// grid: ((nd+3)/4, HDIM/HT1, C2); block: 256 = 4 waves = 4 consecutive d-slices
// buf layout (fp16): [f][c][bd][h][w], bd = d - d0 + 4, fstride = C2*bufD*HWN
__global__ __launch_bounds__(256)
void k_hwsum(const float* __restrict__ I, const float* __restrict__ J,
             __half* __restrict__ buf, int d0, int dbeg, int dend, int bufD)
{
    const int tid = threadIdx.x;
    const int wv  = tid >> 6;
    const int k   = tid & 63;
    const bool act = (k < 48);
    const int w0  = 4 * (act ? k : 0);
    int d = dbeg + 4*blockIdx.x + wv;
    if (d >= dend) d = dend - 1;      // duplicate wave writes identical data
    const int h0 = blockIdx.y * HT1;
    const int c  = blockIdx.z;

    __shared__ float lds[4][5][208];              // W-window rows, 16.6 KB
    __shared__ __align__(16) uint2 stag[4][5][96]; // 2-row fp16 store staging, 15.4 KB

    // zero W-halo pads: float idx 4..7 (w=-4..-1) and 200..203 (w=192..195)
    if (k < 4) {
        #pragma unroll
        for (int f = 0; f < 5; ++f) lds[wv][f][4 + k] = 0.f;
    }
    if (k >= 60) {
        #pragma unroll
        for (int f = 0; f < 5; ++f) lds[wv][f][200 + (k - 60)] = 0.f;
    }

    const float* Ib = I + (size_t)c*VOL + (size_t)d*HWN + w0;
    const float* Jb = J + (size_t)c*VOL + (size_t)d*HWN + w0;

    float4 rs0=zero4(), rs1=zero4(), rs2=zero4(), rs3=zero4(), rs4=zero4();
    float4 rI0,rI1,rI2,rI3,rI4,rI5,rI6,rI7,rI8, rJ0,rJ1,rJ2,rJ3,rJ4,rJ5,rJ6,rJ7,rJ8;
    rI8 = zero4(); rJ8 = zero4();

    // warm-up: ring slots 0..7 = I/J rows h0-4 .. h0+3 (zero padded)
    #define WARM(S, RIS, RJS) { const int h = h0 - RAD + S;                        \
        float4 iv = zero4(), jv = zero4();                                         \
        if (act && h >= 0 && h < HDIM) {                                           \
            iv = *(const float4*)(Ib + (size_t)h*WDIM);                            \
            jv = *(const float4*)(Jb + (size_t)h*WDIM); }                          \
        RIS = iv; RJS = jv; padd(rs0,rs1,rs2,rs3,rs4, iv, jv); }
    WARM(0,rI0,rJ0) WARM(1,rI1,rJ1) WARM(2,rI2,rJ2) WARM(3,rI3,rJ3)
    WARM(4,rI4,rJ4) WARM(5,rI5,rJ5) WARM(6,rI6,rJ6) WARM(7,rI7,rJ7)
    #undef WARM

    // 2-deep prefetch: rows h0+4 (step 0) and h0+5 (step 1); both < HDIM always
    float4 nI0 = zero4(), nJ0 = zero4(), nI1 = zero4(), nJ1 = zero4();
    if (act) {
        nI0 = *(const float4*)(Ib + (size_t)(h0 + RAD)*WDIM);
        nJ0 = *(const float4*)(Jb + (size_t)(h0 + RAD)*WDIM);
        nI1 = *(const float4*)(Ib + (size_t)(h0 + RAD + 1)*WDIM);
        nJ1 = *(const float4*)(Jb + (size_t)(h0 + RAD + 1)*WDIM);
    }

    const size_t fstride = (size_t)C2*bufD*HWN;
    __half* const obase = buf + ((size_t)c*bufD + (size_t)(d - d0 + RAD))*HWN;

    float4* const L0 = (float4*)&lds[wv][0][0];
    float4* const L1 = (float4*)&lds[wv][1][0];
    float4* const L2 = (float4*)&lds[wv][2][0];
    float4* const L3 = (float4*)&lds[wv][3][0];
    float4* const L4 = (float4*)&lds[wv][4][0];

    int i = 0;

    // own 4 H-sums at L[k+2]; window = left L[k+1] | own (reg) | right L[k+3]
    #define FIELDSTAGE(L, RSF, F, PAR) {                                           \
        const float4 A = L[k+1], Cc = L[k+3];                                      \
        const float o0 = ((A.x+A.y)+(A.z+A.w)) + ((RSF.x+RSF.y)+(RSF.z+RSF.w)) + Cc.x; \
        const float o1 = o0 - A.x + Cc.y;                                          \
        const float o2 = o1 - A.y + Cc.z;                                          \
        const float o3 = o2 - A.z + Cc.w;                                          \
        const __half2 ha = __floats2half2_rn(o0, o1);                              \
        const __half2 hb = __floats2half2_rn(o2, o3);                              \
        uint2 u; u.x = __builtin_bit_cast(unsigned int, ha);                       \
        u.y = __builtin_bit_cast(unsigned int, hb);                                \
        stag[wv][F][PAR*48 + k] = u; }

    #define FLUSH(F, H) {                                                          \
        const float4 v = ((const float4*)stag[wv][F])[k];                          \
        *(float4*)(obase + (size_t)F*fstride + (size_t)(H)*WDIM + 8*(size_t)k) = v; }

    #define STEP(PAR, RID, RJD, RIS, RJS) {                                        \
        const int h = h0 + i;                                                      \
        const float4 aI = nI0, aJ = nJ0;                                           \
        nI0 = nI1; nJ0 = nJ1;                                                      \
        nI1 = zero4(); nJ1 = zero4();                                              \
        { const int hf = h + 2 + RAD;                                              \
          if (act && (i + 2 < HT1) && hf < HDIM) {                                 \
              nI1 = *(const float4*)(Ib + (size_t)hf*WDIM);                        \
              nJ1 = *(const float4*)(Jb + (size_t)hf*WDIM); } }                    \
        padd(rs0,rs1,rs2,rs3,rs4, aI, aJ);                                         \
        if (act) { L0[k+2]=rs0; L1[k+2]=rs1; L2[k+2]=rs2; L3[k+2]=rs3; L4[k+2]=rs4; } \
        asm volatile("s_waitcnt lgkmcnt(0)" ::: "memory");                         \
        if (act) { FIELDSTAGE(L0,rs0,0,PAR) FIELDSTAGE(L1,rs1,1,PAR)               \
                   FIELDSTAGE(L2,rs2,2,PAR) FIELDSTAGE(L3,rs3,3,PAR)               \
                   FIELDSTAGE(L4,rs4,4,PAR) }                                      \
        if (PAR) {                                                                 \
            asm volatile("s_waitcnt lgkmcnt(0)" ::: "memory");                     \
            if (act) { FLUSH(0, h-1) FLUSH(1, h-1) FLUSH(2, h-1)                   \
                       FLUSH(3, h-1) FLUSH(4, h-1) }                               \
        }                                                                          \
        psub(rs0,rs1,rs2,rs3,rs4, RID, RJD);                                       \
        RIS = aI; RJS = aJ;                                                        \
        ++i; }

    // 14 steps: drop slot s%9, store slot (s+8)%9
    STEP(0,rI0,rJ0,rI8,rJ8) STEP(1,rI1,rJ1,rI0,rJ0)
    STEP(0,rI2,rJ2,rI1,rJ1) STEP(1,rI3,rJ3,rI2,rJ2)
    STEP(0,rI4,rJ4,rI3,rJ3) STEP(1,rI5,rJ5,rI4,rJ4)
    STEP(0,rI6,rJ6,rI5,rJ5) STEP(1,rI7,rJ7,rI6,rJ6)
    STEP(0,rI8,rJ8,rI7,rJ7) STEP(1,rI0,rJ0,rI8,rJ8)
    STEP(0,rI1,rJ1,rI0,rJ0) STEP(1,rI2,rJ2,rI1,rJ1)
    STEP(0,rI3,rJ3,rI2,rJ2) STEP(1,rI4,rJ4,rI3,rJ3)
    #undef STEP
    #undef FLUSH
    #undef FIELDSTAGE
}

// -------- K2: D-sum (register ring) + cc + block reduce — no LDS, no syncs --------
// grid: (HWN/256, nsub, C2); block: 256 threads
__global__ __launch_bounds__(256)
void k_dsum(const __half* __restrict__ buf, double* __restrict__ gacc,
            int d0, int bufD, int DS)
{
    const int tid = threadIdx.x;
    const int pix = blockIdx.x*256 + tid;     // (h,w) flat, HWN = 168*256 exact
    const int c   = blockIdx.z;
    const int ds0 = d0 + blockIdx.y*DS;

    const size_t fstride = (size_t)C2*bufD*HWN;
    const __half* base = buf + (size_t)c*bufD*HWN + pix;

    float ring[5][9];
    float rs[5] = {0.f,0.f,0.f,0.f,0.f};
    float acc = 0.f;

    // warm-up: slices ds0-4 .. ds0+3
    #pragma unroll
    for (int k = 0; k < 8; ++k) {
        const int dd = ds0 - RAD + k;
        float v[5] = {0.f,0.f,0.f,0.f,0.f};
        if ((unsigned)dd < (unsigned)DDIM) {
            const __half* pp = base + (size_t)(dd - d0 + RAD)*HWN;
            #pragma unroll
            for (int f = 0; f < 5; ++f) v[f] = __half2float(pp[(size_t)f*fstride]);
        }
        #pragma unroll
        for (int f = 0; f < 5; ++f) { ring[f][k] = v[f]; rs[f] += v[f]; }
    }

    int i = 0;
    while (i < DS) {
        #pragma unroll
        for (int p = 0; p < 9; ++p) {   // i == p (mod 9) whenever body runs
            if (i < DS) {
                const int dd = ds0 + i + RAD;
                float v[5] = {0.f,0.f,0.f,0.f,0.f};
                if (dd < DDIM) {
                    const __half* pp = base + (size_t)(dd - d0 + RAD)*HWN;
                    #pragma unroll
                    for (int f = 0; f < 5; ++f) v[f] = __half2float(pp[(size_t)f*fstride]);
                }
                float S[5];
                #pragma unroll
                for (int f = 0; f < 5; ++f) {
                    rs[f] += v[f];              // full 9x9x9 sum at dd-4
                    S[f] = rs[f];
                    rs[f] -= ring[f][p];        // drop slice dd-8
                    ring[f][(p+8)%9] = v[f];    // keep slice dd
                }
                const float uI    = S[0]*WINV;
                const float uJ    = S[1]*WINV;
                const float cross = S[4] - uJ*S[0];
                const float Iv    = S[2] - uI*S[0];
                const float Jv    = S[3] - uJ*S[1];
                acc += cross*cross / (Iv*Jv + 1e-5f);
                ++i;
            }
        }
    }

    // block reduction -> one double atomic per block
    __shared__ float wred[4];
    #pragma unroll
    for (int off = 32; off > 0; off >>= 1) acc += __shfl_down(acc, off);
    if ((tid & 63) == 0) wred[tid >> 6] = acc;
    __syncthreads();
    if (tid == 0) {
        const float sum = wred[0] + wred[1] + wred[2] + wred[3];
        atomicAdd(gacc, (double)sum);
    }
}

__global__ void k_fin(const double* __restrict__ gacc, float* __restrict__ out)
{
    out[0] = (float)(-gacc[0] / (double)((size_t)C2*DDIM*HDIM*WDIM));
}

extern "C" void kernel_launch(void* const* d_in, const int* in_sizes, int n_in,
                              void* d_out, int out_size, void* d_ws, size_t ws_size,
                              hipStream_t stream)
{
    if (n_in < 2) return;
    const float* I = (const float*)d_in[0];
    const float* J = (const float*)d_in[1];
    float* out = (float*)d_out;
    double* gacc = (double*)d_ws;
    __half* buf = (__half*)((char*)d_ws + 256);

    // choose D-chunk so the 5-field fp16 2D-summed buffer fits ws (192 = 1 chunk)
    static const int cands[] = {192, 96, 48, 24, 12, 6, 4, 2, 1};
    int Dc = 0;
    for (int c : cands) {
        const size_t need = 256 + (size_t)5*C2*(c+8)*HWN*sizeof(__half);
        if (need <= ws_size) { Dc = c; break; }
    }
    if (Dc == 0) return;  // ws too small — cannot run

    hipMemsetAsync(d_ws, 0, 256, stream);   // zero the double accumulator

    const int DS   = (Dc % 48 == 0) ? 48 : Dc;  // K2 sub-chunk along D
    const int nsub = Dc / DS;
    const int bufD = Dc + 8;

    for (int d0 = 0; d0 < DDIM; d0 += Dc) {
        const int dbeg = (d0 - RAD < 0) ? 0 : d0 - RAD;
        const int dend = (d0 + Dc + RAD > DDIM) ? DDIM : d0 + Dc + RAD;
        const int nd   = dend - dbeg;
        dim3 g1((nd + 3)/4, HDIM/HT1, C2);
        k_hwsum<<<g1, dim3(256,1,1), 0, stream>>>(I, J, buf, d0, dbeg, dend, bufD);
        dim3 g2(HWN/256, nsub, C2);
        k_dsum<<<g2, dim3(256,1,1), 0, stream>>>(buf, gacc, d0, bufD, DS);
    }
    k_fin<<<1,1,0,stream>>>(gacc, out);
}